// Round 1
// baseline (277.699 us; speedup 1.0000x reference)
//
#include <hip/hip_runtime.h>

// ConvCRF forward, MI355X. Layout decisions:
//  - q lives in d_out (NHWC, same as unaries) across iterations; no init/output transpose.
//  - sm (softmax over BATCH axis, per reference's axis=0!) stored NCHW in d_ws for
//    coalesced per-channel tile loads in the update kernel.
//  - Ms = compat @ spatial_w, Mb = compat @ bilateral_w precomputed (19x19 each).
//  - spatial tap weight exp(-0.5*(dx^2+dy^2)/9) is constant per offset (theta_gamma=3);
//    bilateral weight = same constant * exp(-0.5*||d_rgb||^2/160^2) (theta_beta=3 too).
//  - norms (gaussian of ones) are channel-independent -> two scalars per pixel,
//    accumulated inside the tap loop.

#define HH 160
#define WW 160
#define NC 19
#define SPAN 3
#define FS 7
#define NTAPS 49
#define TILE 16
#define HALO 3
#define LT (TILE + 2*HALO)   // 22

__global__ void prep_kernel(const float* __restrict__ sw, const float* __restrict__ bw,
                            const float* __restrict__ compat,
                            float* __restrict__ Ms, float* __restrict__ Mb) {
    for (int e = threadIdx.x; e < NC*NC; e += blockDim.x) {
        int k = e / NC, c = e % NC;
        float as = 0.f, ab = 0.f;
        for (int j = 0; j < NC; ++j) {
            float ck = compat[k*NC + j];
            as += ck * sw[j*NC + c];
            ab += ck * bw[j*NC + c];
        }
        Ms[e] = as;
        Mb[e] = ab;
    }
}

// softmax over the batch axis (size 2), exactly as reference's softmax(q, axis=0).
// q is NHWC (b,i,j,c); sm written NCHW (b,c,i,j).
__global__ void softmax_kernel(const float* __restrict__ q, float* __restrict__ sm) {
    int idx = blockIdx.x * blockDim.x + threadIdx.x;   // idx over c*H*W (NCHW order)
    if (idx >= NC*HH*WW) return;
    int c = idx / (HH*WW);
    int p = idx % (HH*WW);
    int i = p / WW, j = p % WW;
    int off = (i*WW + j)*NC + c;
    float q0 = q[off];
    float q1 = q[HH*WW*NC + off];
    float m  = fmaxf(q0, q1);
    float e0 = __expf(q0 - m);
    float e1 = __expf(q1 - m);
    float inv = 1.0f / (e0 + e1);
    sm[idx]            = e0 * inv;   // b = 0
    sm[NC*HH*WW + idx] = e1 * inv;   // b = 1
}

__global__ __launch_bounds__(256) void update_kernel(
        const float* __restrict__ sm,   // NCHW
        const float* __restrict__ rgb,  // NHWC, 3 ch
        const float* __restrict__ u,    // NHWC
        const float* __restrict__ Ms, const float* __restrict__ Mb,
        float* __restrict__ qout) {     // NHWC
    __shared__ float smL[NC][LT*LT];
    __shared__ float rgbL[3][LT*LT];
    __shared__ float MsL[NC*NC], MbL[NC*NC];

    const int b   = blockIdx.z;
    const int ti0 = blockIdx.y * TILE;
    const int tj0 = blockIdx.x * TILE;
    const int tid = threadIdx.y * TILE + threadIdx.x;

    for (int e = tid; e < NC*NC; e += 256) { MsL[e] = Ms[e]; MbL[e] = Mb[e]; }

    for (int e = tid; e < LT*LT; e += 256) {
        int r = e / LT, col = e % LT;
        int gi = ti0 - HALO + r, gj = tj0 - HALO + col;
        float rr = 0.f, gg = 0.f, bb = 0.f;
        if (gi >= 0 && gi < HH && gj >= 0 && gj < WW) {
            const float* p = rgb + ((size_t)(b*HH + gi)*WW + gj)*3;
            rr = p[0] * (1.0f/160.0f);
            gg = p[1] * (1.0f/160.0f);
            bb = p[2] * (1.0f/160.0f);
        }
        rgbL[0][e] = rr; rgbL[1][e] = gg; rgbL[2][e] = bb;
    }

    for (int c = 0; c < NC; ++c) {
        const float* smc = sm + ((size_t)(b*NC + c))*HH*WW;
        for (int e = tid; e < LT*LT; e += 256) {
            int r = e / LT, col = e % LT;
            int gi = ti0 - HALO + r, gj = tj0 - HALO + col;
            smL[c][e] = (gi >= 0 && gi < HH && gj >= 0 && gj < WW) ? smc[gi*WW + gj] : 0.0f;
        }
    }
    __syncthreads();

    const int i  = ti0 + threadIdx.y;
    const int j  = tj0 + threadIdx.x;
    const int li = threadIdx.y + HALO;
    const int lj = threadIdx.x + HALO;
    const int center = li*LT + lj;
    const float cr = rgbL[0][center], cg = rgbL[1][center], cb = rgbL[2][center];

    float s_acc[NC], b_acc[NC];
    #pragma unroll
    for (int c = 0; c < NC; ++c) { s_acc[c] = 0.f; b_acc[c] = 0.f; }
    float s_n = 0.f, b_n = 0.f;

    for (int t = 0; t < NTAPS; ++t) {
        const int dx = t / FS - SPAN;   // row offset
        const int dy = t % FS - SPAN;   // col offset
        const int ni = i + dx, nj = j + dy;
        if (ni < 0 || ni >= HH || nj < 0 || nj >= WW) continue;  // mask
        const float wsp = __expf(-0.5f * (float)(dx*dx + dy*dy) * (1.0f/9.0f));
        const int noff = (li + dx)*LT + (lj + dy);
        const float dr = cr - rgbL[0][noff];
        const float dg = cg - rgbL[1][noff];
        const float db = cb - rgbL[2][noff];
        const float wb = wsp * __expf(-0.5f * (dr*dr + dg*dg + db*db));
        s_n += wsp;
        b_n += wb;
        #pragma unroll
        for (int c = 0; c < NC; ++c) {
            const float v = smL[c][noff];
            s_acc[c] += wsp * v;
            b_acc[c] += wb  * v;
        }
    }

    const float s_inv = 1.0f / (s_n + 1e-20f);
    const float b_inv = 1.0f / (b_n + 1e-20f);
    #pragma unroll
    for (int c = 0; c < NC; ++c) { s_acc[c] *= s_inv; b_acc[c] *= b_inv; }

    const float* up = u    + ((size_t)(b*HH + i)*WW + j)*NC;
    float*       qp = qout + ((size_t)(b*HH + i)*WW + j)*NC;
    #pragma unroll
    for (int k = 0; k < NC; ++k) {
        float pw = 0.f;
        #pragma unroll
        for (int c = 0; c < NC; ++c) {
            pw += MsL[k*NC + c] * s_acc[c] + MbL[k*NC + c] * b_acc[c];
        }
        qp[k] = up[k] - pw;   // q = u - pairwise
    }
}

extern "C" void kernel_launch(void* const* d_in, const int* in_sizes, int n_in,
                              void* d_out, int out_size, void* d_ws, size_t ws_size,
                              hipStream_t stream) {
    const float* u      = (const float*)d_in[0];  // (2,160,160,19)
    const float* rgb    = (const float*)d_in[1];  // (2,160,160,3)
    const float* sw     = (const float*)d_in[2];  // (19,19)
    const float* bw     = (const float*)d_in[3];  // (19,19)
    const float* compat = (const float*)d_in[4];  // (19,19)
    float* out = (float*)d_out;                   // q buffer, NHWC

    float* sm = (float*)d_ws;                     // 2*19*160*160 floats (NCHW)
    float* Ms = sm + 2*NC*HH*WW;
    float* Mb = Ms + NC*NC;

    prep_kernel<<<1, 256, 0, stream>>>(sw, bw, compat, Ms, Mb);

    const int n_sm = NC*HH*WW;
    for (int it = 0; it < 5; ++it) {
        const float* src = (it == 0) ? u : out;
        softmax_kernel<<<(n_sm + 255)/256, 256, 0, stream>>>(src, sm);
        update_kernel<<<dim3(WW/TILE, HH/TILE, 2), dim3(TILE, TILE), 0, stream>>>(
            sm, rgb, u, Ms, Mb, out);
    }
}

// Round 2
// 170.306 us; speedup vs baseline: 1.6306x; 1.6306x over previous
//
#include <hip/hip_runtime.h>

// ConvCRF forward, MI355X — round 2.
// Key structure:
//  - prep_kernel: pack u (19ch NHWC) -> uPad (20ch, f4-aligned), rgb -> rgbPad
//    (float4, pre-scaled by 1/160), and M = [compat@sw | compat@bw] (19x40, zero-padded).
//  - update_kernel x5: 8x8 pixel tile per 64-thread (1-wave) block, grid 20x20x2=800.
//    Fuses batch-axis softmax (reads both batches' q at halo pixels), 7x7 dual-filter
//    gaussian with channel-independent norms, 19x38 matvec epilogue, q = u - pairwise.
//  - LDS: smL as float4 groups [g][pixel] (channel-contiguous, ds_read_b128,
//    linear lane addresses -> no bank conflicts); rgbL.w carries the boundary mask
//    so the tap loop is branch-free.
//  - q ping-pongs through two padded ws buffers; final iteration writes d_out (19ch).

#define HH 160
#define WW 160
#define NPIX (HH*WW)      // 25600
#define NC 19
#define CH 20             // padded channel count (float4-friendly)
#define NG 5              // CH/4
#define SPAN 3
#define TILE 8
#define LT 14             // TILE + 2*SPAN
#define NHALO (LT*LT)     // 196
#define LTP 208           // padded pixel stride for LDS f4 arrays
#define EPSF 1e-20f

__device__ __forceinline__ float fast_rcp(float x) { return __builtin_amdgcn_rcpf(x); }

__global__ __launch_bounds__(256) void prep_kernel(
        const float* __restrict__ u, const float* __restrict__ rgb,
        const float* __restrict__ sw, const float* __restrict__ bw,
        const float* __restrict__ compat,
        float* __restrict__ uPad, float4* __restrict__ rgbPad, float* __restrict__ M) {
    const int e = blockIdx.x * 256 + threadIdx.x;

    if (e < 2 * NPIX * CH) {
        const int p = e / CH, c = e % CH;
        uPad[e] = (c < NC) ? u[p * NC + c] : 0.0f;
    }
    if (e < 2 * NPIX) {
        rgbPad[e] = make_float4(rgb[3*e+0] * (1.0f/160.0f),
                                rgb[3*e+1] * (1.0f/160.0f),
                                rgb[3*e+2] * (1.0f/160.0f), 0.0f);
    }
    if (e < NC * 40) {
        const int k = e / 40, c = e % 40;
        float acc = 0.0f;
        if (c < NC) {
            for (int j = 0; j < NC; ++j) acc += compat[k*NC + j] * sw[j*NC + c];
        } else if (c >= CH && c < CH + NC) {
            const int cc = c - CH;
            for (int j = 0; j < NC; ++j) acc += compat[k*NC + j] * bw[j*NC + cc];
        }
        M[e] = acc;   // pads (c==19, c==39) stay 0 -> channel-19 garbage is masked
    }
}

__device__ __forceinline__ float smx(float q0, float q1, int b) {
    const float m  = fmaxf(q0, q1);
    const float e0 = __expf(q0 - m);
    const float e1 = __expf(q1 - m);
    return (b == 0 ? e0 : e1) * fast_rcp(e0 + e1);
}

__global__ __launch_bounds__(64) void update_kernel(
        const float4* __restrict__ qsrc,   // padded CH-ch NHWC, both batches
        const float4* __restrict__ rgbPad, // pre-scaled rgb, w unused
        const float4* __restrict__ uPad,   // padded unaries
        const float*  __restrict__ M,      // 19x40 [Ms | Mb], uniform reads
        float*        __restrict__ outF,   // final output (19ch NHWC) when final
        float4*       __restrict__ outP,   // padded q dst otherwise
        const int final_flag) {
    __shared__ float4 smL[NG * LTP];
    __shared__ float4 rgbL[LTP];

    const int b   = blockIdx.z;
    const int ti0 = blockIdx.y * TILE;
    const int tj0 = blockIdx.x * TILE;
    const int tid = threadIdx.x;

    // ---- halo load + fused batch-axis softmax ----
    for (int e = tid; e < NHALO; e += 64) {
        const int r  = e / LT, c2 = e % LT;
        const int gi = ti0 - SPAN + r, gj = tj0 - SPAN + c2;
        const bool valid = (gi >= 0 && gi < HH && gj >= 0 && gj < WW);
        if (valid) {
            const int p = gi * WW + gj;
            const float4* q0 = qsrc + (size_t)p * NG;
            const float4* q1 = qsrc + (size_t)(NPIX + p) * NG;
            #pragma unroll
            for (int g = 0; g < NG; ++g) {
                const float4 a = q0[g];
                const float4 d = q1[g];
                float4 o;
                o.x = smx(a.x, d.x, b);
                o.y = smx(a.y, d.y, b);
                o.z = smx(a.z, d.z, b);
                o.w = smx(a.w, d.w, b);
                smL[g * LTP + e] = o;
            }
            float4 rv = rgbPad[b * NPIX + p];
            rv.w = 1.0f;                       // validity flag
            rgbL[e] = rv;
        } else {
            #pragma unroll
            for (int g = 0; g < NG; ++g) smL[g * LTP + e] = make_float4(0,0,0,0);
            rgbL[e] = make_float4(0,0,0,0);
        }
    }
    __syncthreads();

    // ---- per-pixel dual-filter taps ----
    const int ty = tid >> 3, tx = tid & 7;
    const int i  = ti0 + ty, j = tj0 + tx;
    const int li = ty + SPAN, lj = tx + SPAN;
    const float4 crv = rgbL[li * LT + lj];

    float sa[CH], ba[CH];
    #pragma unroll
    for (int c = 0; c < CH; ++c) { sa[c] = 0.0f; ba[c] = 0.0f; }
    float s_n = 0.0f, b_n = 0.0f;

    for (int dx = -SPAN; dx <= SPAN; ++dx) {
        const int rowb = (li + dx) * LT + lj;
        #pragma unroll
        for (int dy = -SPAN; dy <= SPAN; ++dy) {
            const int noff = rowb + dy;
            const float4 rv = rgbL[noff];
            const float wsp = __expf(-0.5f * (float)(dx*dx + dy*dy) * (1.0f/9.0f)) * rv.w;
            const float dr = crv.x - rv.x, dg = crv.y - rv.y, db = crv.z - rv.z;
            const float wb = wsp * __expf(-0.5f * (dr*dr + dg*dg + db*db));
            s_n += wsp;
            b_n += wb;
            #pragma unroll
            for (int g = 0; g < NG; ++g) {
                const float4 v = smL[g * LTP + noff];
                sa[4*g+0] += wsp * v.x; sa[4*g+1] += wsp * v.y;
                sa[4*g+2] += wsp * v.z; sa[4*g+3] += wsp * v.w;
                ba[4*g+0] += wb  * v.x; ba[4*g+1] += wb  * v.y;
                ba[4*g+2] += wb  * v.z; ba[4*g+3] += wb  * v.w;
            }
        }
    }

    const float sinv = fast_rcp(s_n + EPSF);
    const float binv = fast_rcp(b_n + EPSF);
    #pragma unroll
    for (int c = 0; c < CH; ++c) { sa[c] *= sinv; ba[c] *= binv; }

    // ---- epilogue: q = u - Ms*s - Mb*b ----
    const int p = b * NPIX + i * WW + j;
    float uv[CH];
    const float4* up = uPad + (size_t)p * NG;
    #pragma unroll
    for (int g = 0; g < NG; ++g) {
        const float4 t = up[g];
        uv[4*g+0] = t.x; uv[4*g+1] = t.y; uv[4*g+2] = t.z; uv[4*g+3] = t.w;
    }

    float outv[CH];
    #pragma unroll
    for (int k = 0; k < NC; ++k) {
        const float* mk = M + k * 40;     // uniform address -> scalar loads
        float pw = 0.0f;
        #pragma unroll
        for (int c = 0; c < NC; ++c) pw += mk[c] * sa[c] + mk[CH + c] * ba[c];
        outv[k] = uv[k] - pw;
    }
    outv[NC] = 0.0f;

    if (final_flag) {
        float* op = outF + (size_t)p * NC;
        #pragma unroll
        for (int k = 0; k < NC; ++k) op[k] = outv[k];
    } else {
        float4* op = outP + (size_t)p * NG;
        #pragma unroll
        for (int g = 0; g < NG; ++g)
            op[g] = make_float4(outv[4*g+0], outv[4*g+1], outv[4*g+2], outv[4*g+3]);
    }
}

extern "C" void kernel_launch(void* const* d_in, const int* in_sizes, int n_in,
                              void* d_out, int out_size, void* d_ws, size_t ws_size,
                              hipStream_t stream) {
    const float* u      = (const float*)d_in[0];  // (2,160,160,19)
    const float* rgb    = (const float*)d_in[1];  // (2,160,160,3)
    const float* sw     = (const float*)d_in[2];
    const float* bw     = (const float*)d_in[3];
    const float* compat = (const float*)d_in[4];
    float* out = (float*)d_out;

    const size_t NPAD = (size_t)2 * NPIX * CH;    // 1,024,000 floats
    float*  uPad   = (float*)d_ws;
    float*  qA     = uPad + NPAD;
    float*  qB     = qA + NPAD;
    float4* rgbPad = (float4*)(qB + NPAD);        // byte offset 12,288,000 (16B-aligned)
    float*  M      = (float*)(rgbPad + 2 * NPIX);

    prep_kernel<<<(2*NPIX*CH + 255)/256, 256, 0, stream>>>(u, rgb, sw, bw, compat,
                                                           uPad, rgbPad, M);

    const dim3 grid(WW/TILE, HH/TILE, 2), blk(64);
    const float* srcs[5] = { uPad, qA, qB, qA, qB };
    float*       dsts[5] = { qA,   qB, qA, qB, nullptr };
    for (int it = 0; it < 5; ++it) {
        const int fin = (it == 4);
        update_kernel<<<grid, blk, 0, stream>>>(
            (const float4*)srcs[it], rgbPad, (const float4*)uPad, M,
            fin ? out : nullptr, fin ? nullptr : (float4*)dsts[it], fin);
    }
}